// Round 4
// baseline (23.602 us; speedup 1.0000x reference)
//
#include <hip/hip_runtime.h>
#include <math.h>

#define HID 5
#define NTAB 27

__device__ __forceinline__ float sigm(float x) { return 1.0f / (1.0f + expf(-x)); }
__device__ __forceinline__ float softplus_f(float x) {
    return fmaxf(x, 0.0f) + log1pf(expf(-fabsf(x)));
}

// table value lives in lane (idx) of every wave; gather with a 64-wide shuffle
__device__ __forceinline__ float samp(float tval, float x, float l, float g) {
    int sx = (x > 0.0f) - (x < 0.0f);
    int sl = (l > 0.0f) - (l < 0.0f);
    int sg = (g > 0.0f) - (g < 0.0f);
    int idx = (sx + 1) * 9 + (sl + 1) * 3 + (sg + 1);   // 0..26
    float tv = __shfl(tval, idx, 64);
    float ax = fabsf(x);
    return tv * ((ax > 0.0f) ? ax : 1.0f);
}

__global__ __launch_bounds__(256) void lstm_opt_wave(
    const float* __restrict__ bx, const float* __restrict__ bl, const float* __restrict__ bg,
    const float* __restrict__ W_ih1, const float* __restrict__ W_hh1,
    const float* __restrict__ b_ih1, const float* __restrict__ b_hh1,
    const float* __restrict__ W_ih2, const float* __restrict__ W_hh2,
    const float* __restrict__ b_ih2, const float* __restrict__ b_hh2,
    const float* __restrict__ W_out, const float* __restrict__ b_out,
    const float* __restrict__ h1_0, const float* __restrict__ c1_0,
    const float* __restrict__ h2_0, const float* __restrict__ c2_0,
    const float* __restrict__ poly, const int* __restrict__ t_ptr,
    float* __restrict__ out, int N)
{
    const int tid = threadIdx.x;
    const int lane = tid & 63;

    const int gtid = blockIdx.x * blockDim.x + tid;
    const int gstride = gridDim.x * blockDim.x;
    const int nvec = N >> 2;

    const float4* bx4 = reinterpret_cast<const float4*>(bx);
    const float4* bl4 = reinterpret_cast<const float4*>(bl);
    const float4* bg4 = reinterpret_cast<const float4*>(bg);
    float4* out4 = reinterpret_cast<float4*>(out);

    // ---- issue this thread's first streaming loads NOW (in flight during LUT) ----
    float4 x0, l0, g0;
    bool have0 = (gtid < nvec);
    if (have0) { x0 = bx4[gtid]; l0 = bl4[gtid]; g0 = bg4[gtid]; }

    // ---- per-wave LUT: lane i (< 27) computes table entry i; no LDS, no barrier ----
    // Weight addresses are wave-uniform -> compiler emits scalar loads.
    {
        int li = (lane < NTAB) ? lane : 0;
        float gn = (float)(li % 3) - 1.0f;
        float ln = (float)((li / 3) % 3) - 1.0f;
        float xn = (float)(li / 9) - 1.0f;

        float h1[HID];
        #pragma unroll
        for (int j = 0; j < HID; ++j) {
            float gk[4];
            #pragma unroll
            for (int q = 0; q < 4; ++q) {
                int k = j + q * HID;
                float acc = b_ih1[k] + b_hh1[k];
                #pragma unroll
                for (int m = 0; m < HID; ++m) acc += W_hh1[k * HID + m] * h1_0[m];
                acc += W_ih1[k * 3 + 0] * xn + W_ih1[k * 3 + 1] * ln + W_ih1[k * 3 + 2] * gn;
                gk[q] = acc;
            }
            float c = sigm(gk[1]) * c1_0[j] + sigm(gk[0]) * tanhf(gk[2]);
            h1[j] = sigm(gk[3]) * tanhf(c);
        }

        float h2v[HID];
        #pragma unroll
        for (int j = 0; j < HID; ++j) {
            float gk[4];
            #pragma unroll
            for (int q = 0; q < 4; ++q) {
                int k = j + q * HID;
                float acc = b_ih2[k] + b_hh2[k];
                #pragma unroll
                for (int m = 0; m < HID; ++m) acc += W_hh2[k * HID + m] * h2_0[m];
                #pragma unroll
                for (int m = 0; m < HID; ++m) acc += W_ih2[k * HID + m] * h1[m];
                gk[q] = acc;
            }
            float c = sigm(gk[1]) * c2_0[j] + sigm(gk[0]) * tanhf(gk[2]);
            h2v[j] = sigm(gk[3]) * tanhf(c);
        }

        float v = b_out[0];
        #pragma unroll
        for (int m = 0; m < HID; ++m) v += W_out[m] * h2v[m];

        int t = *t_ptr;
        float tf = (float)t;
        float pv = 0.0f, p = 1.0f;   // t^0 == 1 even for t==0 (matches Python)
        #pragma unroll
        for (int jj = 0; jj < 4; ++jj) { pv += softplus_f(poly[jj]) * p; p *= tf; }
        float gt = exp2f(tf * -0.0144995696951150f);   // 0.99^t = 2^(t*log2(0.99))

        // tval lives in this lane's register for the whole kernel
        float tval = pv * gt * tanhf(v);

        // ---- streaming ----
        if (have0) {
            float4 o;
            o.x = samp(tval, x0.x, l0.x, g0.x);
            o.y = samp(tval, x0.y, l0.y, g0.y);
            o.z = samp(tval, x0.z, l0.z, g0.z);
            o.w = samp(tval, x0.w, l0.w, g0.w);
            out4[gtid] = o;
        }
        for (int i = gtid + gstride; i < nvec; i += gstride) {
            float4 x = bx4[i];
            float4 l = bl4[i];
            float4 g = bg4[i];
            float4 o;
            o.x = samp(tval, x.x, l.x, g.x);
            o.y = samp(tval, x.y, l.y, g.y);
            o.z = samp(tval, x.z, l.z, g.z);
            o.w = samp(tval, x.w, l.w, g.w);
            out4[i] = o;
        }
        // tail (N % 4)
        for (int i = (nvec << 2) + gtid; i < N; i += gstride) {
            out[i] = samp(tval, bx[i], bl[i], bg[i]);
        }
    }
}

extern "C" void kernel_launch(void* const* d_in, const int* in_sizes, int n_in,
                              void* d_out, int out_size, void* d_ws, size_t ws_size,
                              hipStream_t stream) {
    const float* bx    = (const float*)d_in[0];
    const float* bl    = (const float*)d_in[1];
    const float* bg    = (const float*)d_in[2];
    const float* W_ih1 = (const float*)d_in[3];
    const float* W_hh1 = (const float*)d_in[4];
    const float* b_ih1 = (const float*)d_in[5];
    const float* b_hh1 = (const float*)d_in[6];
    const float* W_ih2 = (const float*)d_in[7];
    const float* W_hh2 = (const float*)d_in[8];
    const float* b_ih2 = (const float*)d_in[9];
    const float* b_hh2 = (const float*)d_in[10];
    const float* W_out = (const float*)d_in[11];
    const float* b_out = (const float*)d_in[12];
    const float* h1_0  = (const float*)d_in[13];
    const float* c1_0  = (const float*)d_in[14];
    const float* h2_0  = (const float*)d_in[15];
    const float* c2_0  = (const float*)d_in[16];
    const float* poly  = (const float*)d_in[17];
    const int*   t_ptr = (const int*)d_in[18];
    float* out = (float*)d_out;

    int N = in_sizes[0];
    int nvec = N >> 2;
    int blocks = (nvec + 255) / 256;
    if (blocks < 1) blocks = 1;
    if (blocks > 2048) blocks = 2048;

    lstm_opt_wave<<<blocks, 256, 0, stream>>>(
        bx, bl, bg, W_ih1, W_hh1, b_ih1, b_hh1,
        W_ih2, W_hh2, b_ih2, b_hh2, W_out, b_out,
        h1_0, c1_0, h2_0, c2_0, poly, t_ptr, out, N);
}

// Round 5
// 15.729 us; speedup vs baseline: 1.5006x; 1.5006x over previous
//
#include <hip/hip_runtime.h>
#include <math.h>

#define HID 5
#define NTAB 27

__device__ __forceinline__ float sigm(float x) { return 1.0f / (1.0f + expf(-x)); }
__device__ __forceinline__ float softplus_f(float x) {
    return fmaxf(x, 0.0f) + log1pf(expf(-fabsf(x)));
}

__device__ __forceinline__ float sample_out(const float* __restrict__ tab,
                                            float x, float l, float g) {
    int sx = (x > 0.0f) - (x < 0.0f);
    int sl = (l > 0.0f) - (l < 0.0f);
    int sg = (g > 0.0f) - (g < 0.0f);
    float ax = fabsf(x);
    float scale = (ax > 0.0f) ? ax : 1.0f;
    return tab[(sx + 1) * 9 + (sl + 1) * 3 + (sg + 1)] * scale;
}

// __launch_bounds__(256, 4): 4 waves/EU min -> VGPR cap 64 (not the compiler's
// default 20-VGPR clamp, which forced preloads to sink below the LUT chain).
__global__ __launch_bounds__(256, 4) void lstm_opt_v5(
    const float* __restrict__ bx, const float* __restrict__ bl, const float* __restrict__ bg,
    const float* __restrict__ W_ih1, const float* __restrict__ W_hh1,
    const float* __restrict__ b_ih1, const float* __restrict__ b_hh1,
    const float* __restrict__ W_ih2, const float* __restrict__ W_hh2,
    const float* __restrict__ b_ih2, const float* __restrict__ b_hh2,
    const float* __restrict__ W_out, const float* __restrict__ b_out,
    const float* __restrict__ h1_0, const float* __restrict__ c1_0,
    const float* __restrict__ h2_0, const float* __restrict__ c2_0,
    const float* __restrict__ poly, const int* __restrict__ t_ptr,
    float* __restrict__ out, int N)
{
    __shared__ float s_table[32];
    const int tid = threadIdx.x;

    const int gtid = blockIdx.x * blockDim.x + tid;
    const int gstride = gridDim.x * blockDim.x;
    const int nvec = N >> 2;

    const float4* bx4 = reinterpret_cast<const float4*>(bx);
    const float4* bl4 = reinterpret_cast<const float4*>(bl);
    const float4* bg4 = reinterpret_cast<const float4*>(bg);
    float4* out4 = reinterpret_cast<float4*>(out);

    // ---- PHASE 1: issue this thread's entire input fetch (one vec4 triple) ----
    float4 x0, l0, g0;
    bool have0 = (gtid < nvec);
    if (have0) { x0 = bx4[gtid]; l0 = bl4[gtid]; g0 = bg4[gtid]; }
    // Pin the loads above the LUT chain: compiler may not sink them below this.
    asm volatile("" ::: "memory");

    // ---- PHASE 2: lanes 0..26 of wave 0 compute the LUT while loads fly ----
    if (tid < NTAB) {
        float gn = (float)(tid % 3) - 1.0f;
        float ln = (float)((tid / 3) % 3) - 1.0f;
        float xn = (float)(tid / 9) - 1.0f;

        float h1[HID];
        #pragma unroll
        for (int j = 0; j < HID; ++j) {
            float gk[4];
            #pragma unroll
            for (int q = 0; q < 4; ++q) {
                int k = j + q * HID;
                float acc = b_ih1[k] + b_hh1[k];
                #pragma unroll
                for (int m = 0; m < HID; ++m) acc += W_hh1[k * HID + m] * h1_0[m];
                acc += W_ih1[k * 3 + 0] * xn + W_ih1[k * 3 + 1] * ln + W_ih1[k * 3 + 2] * gn;
                gk[q] = acc;
            }
            float c = sigm(gk[1]) * c1_0[j] + sigm(gk[0]) * tanhf(gk[2]);
            h1[j] = sigm(gk[3]) * tanhf(c);
        }

        float h2v[HID];
        #pragma unroll
        for (int j = 0; j < HID; ++j) {
            float gk[4];
            #pragma unroll
            for (int q = 0; q < 4; ++q) {
                int k = j + q * HID;
                float acc = b_ih2[k] + b_hh2[k];
                #pragma unroll
                for (int m = 0; m < HID; ++m) acc += W_hh2[k * HID + m] * h2_0[m];
                #pragma unroll
                for (int m = 0; m < HID; ++m) acc += W_ih2[k * HID + m] * h1[m];
                gk[q] = acc;
            }
            float c = sigm(gk[1]) * c2_0[j] + sigm(gk[0]) * tanhf(gk[2]);
            h2v[j] = sigm(gk[3]) * tanhf(c);
        }

        float v = b_out[0];
        #pragma unroll
        for (int m = 0; m < HID; ++m) v += W_out[m] * h2v[m];

        int t = *t_ptr;
        float tf = (float)t;
        float pv = 0.0f, p = 1.0f;   // t^0 == 1 even for t==0 (matches Python)
        #pragma unroll
        for (int jj = 0; jj < 4; ++jj) { pv += softplus_f(poly[jj]) * p; p *= tf; }
        float gt = exp2f(tf * -0.0144995696951150f);   // 0.99^t

        s_table[tid] = pv * gt * tanhf(v);
    }
    __syncthreads();

    // ---- PHASE 3: consume the already-loaded data, store ----
    if (have0) {
        float4 o;
        o.x = sample_out(s_table, x0.x, l0.x, g0.x);
        o.y = sample_out(s_table, x0.y, l0.y, g0.y);
        o.z = sample_out(s_table, x0.z, l0.z, g0.z);
        o.w = sample_out(s_table, x0.w, l0.w, g0.w);
        out4[gtid] = o;
    }
    // safety net (no-op when grid covers nvec exactly)
    for (int i = gtid + gstride; i < nvec; i += gstride) {
        float4 x = bx4[i];
        float4 l = bl4[i];
        float4 g = bg4[i];
        float4 o;
        o.x = sample_out(s_table, x.x, l.x, g.x);
        o.y = sample_out(s_table, x.y, l.y, g.y);
        o.z = sample_out(s_table, x.z, l.z, g.z);
        o.w = sample_out(s_table, x.w, l.w, g.w);
        out4[i] = o;
    }
    for (int i = (nvec << 2) + gtid; i < N; i += gstride) {
        out[i] = sample_out(s_table, bx[i], bl[i], bg[i]);
    }
}

extern "C" void kernel_launch(void* const* d_in, const int* in_sizes, int n_in,
                              void* d_out, int out_size, void* d_ws, size_t ws_size,
                              hipStream_t stream) {
    const float* bx    = (const float*)d_in[0];
    const float* bl    = (const float*)d_in[1];
    const float* bg    = (const float*)d_in[2];
    const float* W_ih1 = (const float*)d_in[3];
    const float* W_hh1 = (const float*)d_in[4];
    const float* b_ih1 = (const float*)d_in[5];
    const float* b_hh1 = (const float*)d_in[6];
    const float* W_ih2 = (const float*)d_in[7];
    const float* W_hh2 = (const float*)d_in[8];
    const float* b_ih2 = (const float*)d_in[9];
    const float* b_hh2 = (const float*)d_in[10];
    const float* W_out = (const float*)d_in[11];
    const float* b_out = (const float*)d_in[12];
    const float* h1_0  = (const float*)d_in[13];
    const float* c1_0  = (const float*)d_in[14];
    const float* h2_0  = (const float*)d_in[15];
    const float* c2_0  = (const float*)d_in[16];
    const float* poly  = (const float*)d_in[17];
    const int*   t_ptr = (const int*)d_in[18];
    float* out = (float*)d_out;

    int N = in_sizes[0];
    int nvec = N >> 2;
    int blocks = (nvec + 255) / 256;
    if (blocks < 1) blocks = 1;
    if (blocks > 2048) blocks = 2048;

    lstm_opt_v5<<<blocks, 256, 0, stream>>>(
        bx, bl, bg, W_ih1, W_hh1, b_ih1, b_hh1,
        W_ih2, W_hh2, b_ih2, b_hh2, W_out, b_out,
        h1_0, c1_0, h2_0, c2_0, poly, t_ptr, out, N);
}